// Round 9
// baseline (535.134 us; speedup 1.0000x reference)
//
#include <hip/hip_runtime.h>
#include <math.h>
#include <type_traits>

#define NNODES 100000
#define NEDGES 1600000
#define NGRAPH 128

typedef _Float16 f16x4 __attribute__((ext_vector_type(4)));
typedef _Float16 f16x8 __attribute__((ext_vector_type(8)));
typedef float f32x4 __attribute__((ext_vector_type(4)));

// ------- MFMA GEMM + fused attention-logit epilogue -------
template <int K, int N, typename AT>
__global__ __launch_bounds__(256, 2) void gemm_mfma(const AT* __restrict__ A,
    const float* __restrict__ B, _Float16* __restrict__ C, int M,
    const float* __restrict__ a_src, const float* __restrict__ a_dst,
    float* __restrict__ asrc, float* __restrict__ adst) {
  constexpr int BM = 64;
  constexpr int H = N / 64;
  __shared__ _Float16 As[BM * K];
  __shared__ _Float16 Bs[N * K];
  const int tid = threadIdx.x;
  const int bm = blockIdx.x * BM;

  for (int i = tid * 4; i < BM * K; i += 1024) {
    int row = i / K;
    int k = i & (K - 1);
    int gr = bm + row;
    f16x4 h;
    if constexpr (std::is_same<AT, float>::value) {
      float4 v = {0.f, 0.f, 0.f, 0.f};
      if (gr < M) v = *(const float4*)&A[(size_t)gr * K + k];
      h[0] = (_Float16)v.x; h[1] = (_Float16)v.y; h[2] = (_Float16)v.z; h[3] = (_Float16)v.w;
    } else {
      f16x4 v = {};
      if (gr < M) v = *(const f16x4*)&A[(size_t)gr * K + k];
      h = v;
    }
    int idx = (row * K + k) ^ ((row & 7) << 3);
    *(f16x4*)&As[idx] = h;
  }
  for (int i = tid * 4; i < N * K; i += 1024) {
    int row = i / K;
    int k = i & (K - 1);
    float4 v = *(const float4*)&B[(size_t)row * K + k];
    f16x4 h;
    h[0] = (_Float16)v.x; h[1] = (_Float16)v.y; h[2] = (_Float16)v.z; h[3] = (_Float16)v.w;
    int idx = (row * K + k) ^ ((row & 7) << 3);
    *(f16x4*)&Bs[idx] = h;
  }
  __syncthreads();

  const int lane = tid & 63, wid = tid >> 6;
  const int lr = lane & 15;
  const int lk = (lane >> 4) * 8;
  constexpr int KS = K / 32, NT = N / 16;

  f16x8 a[KS];
#pragma unroll
  for (int ks = 0; ks < KS; ++ks) {
    int row = wid * 16 + lr;
    int idx = (row * K + ks * 32 + lk) ^ ((row & 7) << 3);
    a[ks] = *(const f16x8*)&As[idx];
  }

  f32x4 acc[NT];
#pragma unroll
  for (int nt = 0; nt < NT; ++nt) acc[nt] = (f32x4){0.f, 0.f, 0.f, 0.f};

#pragma unroll
  for (int nt = 0; nt < NT; ++nt)
#pragma unroll
    for (int ks = 0; ks < KS; ++ks) {
      int row = nt * 16 + lr;
      int idx = (row * K + ks * 32 + lk) ^ ((row & 7) << 3);
      f16x8 b = *(const f16x8*)&Bs[idx];
      acc[nt] = __builtin_amdgcn_mfma_f32_16x16x32_f16(a[ks], b, acc[nt], 0, 0, 0);
    }

  float cs[NT], cd[NT];
#pragma unroll
  for (int nt = 0; nt < NT; ++nt) {
    cs[nt] = a_src[nt * 16 + lr];
    cd[nt] = a_dst[nt * 16 + lr];
  }

  int row0 = bm + wid * 16 + (lane >> 4) * 4;
#pragma unroll
  for (int r = 0; r < 4; ++r) {
    int row = row0 + r;
    float ps[H], pd[H];
#pragma unroll
    for (int h = 0; h < H; ++h) { ps[h] = 0.f; pd[h] = 0.f; }
#pragma unroll
    for (int nt = 0; nt < NT; ++nt) {
      int h = nt >> 2;
      if (H == 1) h = 0;
      ps[h] = fmaf(acc[nt][r], cs[nt], ps[h]);
      pd[h] = fmaf(acc[nt][r], cd[nt], pd[h]);
    }
#pragma unroll
    for (int o = 1; o < 16; o <<= 1) {
#pragma unroll
      for (int h = 0; h < H; ++h) {
        ps[h] += __shfl_xor(ps[h], o);
        pd[h] += __shfl_xor(pd[h], o);
      }
    }
    if (row < M) {
#pragma unroll
      for (int nt = 0; nt < NT; ++nt) C[(size_t)row * N + nt * 16 + lr] = (_Float16)acc[nt][r];
      if (lr == 0) {
        if (H == 4) {
          *(float4*)&asrc[row * 4] = make_float4(ps[0], ps[1], ps[2], ps[3 % H]);
          *(float4*)&adst[row * 4] = make_float4(pd[0], pd[1], pd[2], pd[3 % H]);
        } else {
          asrc[row] = ps[0];
          adst[row] = pd[0];
        }
      }
    }
  }
}

// ---------------- CSR build ----------------
__global__ void hist_kernel(const int* __restrict__ dstv, int* __restrict__ deg, int e_count) {
  int e = blockIdx.x * blockDim.x + threadIdx.x;
  if (e < e_count) atomicAdd(&deg[dstv[e]], 1);
}

__global__ __launch_bounds__(1024) void scan1(const int* __restrict__ deg, int* __restrict__ inc,
                                              int* __restrict__ bsum, int n) {
  __shared__ int sm[1024];
  int i = blockIdx.x * 1024 + threadIdx.x;
  sm[threadIdx.x] = (i < n) ? deg[i] : 0;
  __syncthreads();
  for (int o = 1; o < 1024; o <<= 1) {
    int t = (threadIdx.x >= o) ? sm[threadIdx.x - o] : 0;
    __syncthreads();
    sm[threadIdx.x] += t;
    __syncthreads();
  }
  if (i < n) inc[i] = sm[threadIdx.x];
  if (threadIdx.x == 1023) bsum[blockIdx.x] = sm[1023];
}

__global__ void scan2(const int* __restrict__ bsum, int* __restrict__ boff, int nb) {
  __shared__ int sm[128];
  int t = threadIdx.x;
  int own = (t < nb) ? bsum[t] : 0;
  sm[t] = own;
  __syncthreads();
  for (int o = 1; o < 128; o <<= 1) {
    int u = (t >= o) ? sm[t - o] : 0;
    __syncthreads();
    sm[t] += u;
    __syncthreads();
  }
  if (t < nb) boff[t] = sm[t] - own;
}

__global__ void scan3(const int* __restrict__ inc, const int* __restrict__ deg,
                      const int* __restrict__ boff, int* __restrict__ offsets,
                      int* __restrict__ cursor, int n, int e_count) {
  int i = blockIdx.x * blockDim.x + threadIdx.x;
  if (i < n) {
    int v = inc[i] - deg[i] + boff[i >> 10];
    offsets[i] = v;
    cursor[i] = v;
  }
  if (i == 0) offsets[n] = e_count;
}

__global__ void scatter_kernel(const int* __restrict__ srcv, const int* __restrict__ dstv,
                               int* __restrict__ cursor, int* __restrict__ esrc, int e_count) {
  int e = blockIdx.x * blockDim.x + threadIdx.x;
  if (e < e_count) {
    int p = atomicAdd(&cursor[dstv[e]], 1);
    esrc[p] = srcv[e];
  }
}

// ------------- layer-1 aggregation: one WAVE per node, 8-deep gather pipeline ---
__global__ __launch_bounds__(256) void agg1_kernel(const _Float16* __restrict__ hmat,
    const float* __restrict__ asrc, const float* __restrict__ adst,
    const int* __restrict__ offsets, const int* __restrict__ esrc,
    const float* __restrict__ bias, _Float16* __restrict__ outv, int node0) {
  const int lane = threadIdx.x & 63, wid = threadIdx.x >> 6;
  const int node = node0 + blockIdx.x * 4 + wid;
  if (node >= NNODES) return;
  const int h = lane >> 4;
  const int start = offsets[node];
  const int end = offsets[node + 1];
  const float adn = adst[node * 4 + h];
  const _Float16* hbase = hmat + lane * 4;
  float acc[4] = {0.f, 0.f, 0.f, 0.f};
  float s = 0.f;
  int j = start;
  for (; j + 8 <= end; j += 8) {
    int sv[8];
#pragma unroll
    for (int t = 0; t < 8; ++t) sv[t] = esrc[j + t];
    f16x4 vv[8];
#pragma unroll
    for (int t = 0; t < 8; ++t) vv[t] = *(const f16x4*)&hbase[(size_t)sv[t] * 256];
    _Float16 ph[8];
#pragma unroll
    for (int t = 0; t < 8; ++t) {
      float v = asrc[sv[t] * 4 + h] + adn;
      v = (v > 0.f) ? v : 0.2f * v;
      float p = __expf(v);
      s += p;
      ph[t] = (_Float16)p;
    }
#pragma unroll
    for (int t = 0; t < 8; ++t)
#pragma unroll
      for (int k = 0; k < 4; ++k)
        acc[k] = fmaf((float)vv[t][k], (float)ph[t], acc[k]);  // v_fma_mix_f32
  }
  for (; j < end; ++j) {
    int sv = esrc[j];
    f16x4 vv = *(const f16x4*)&hbase[(size_t)sv * 256];
    float v = asrc[sv * 4 + h] + adn;
    v = (v > 0.f) ? v : 0.2f * v;
    float p = __expf(v);
    s += p;
    _Float16 phs = (_Float16)p;
#pragma unroll
    for (int k = 0; k < 4; ++k) acc[k] = fmaf((float)vv[k], (float)phs, acc[k]);
  }
  float inv = 1.f / (s + 1e-16f);
  f16x4 ho;
#pragma unroll
  for (int k = 0; k < 4; ++k)
    ho[k] = (_Float16)fmaxf(fmaf(acc[k], inv, bias[lane * 4 + k]), 0.f);
  *(f16x4*)&outv[(size_t)node * 256 + lane * 4] = ho;
}

// ------------- layer-2 aggregation: one NODE per 16-lane group, no reduction ----
__global__ __launch_bounds__(256) void agg2_kernel(const _Float16* __restrict__ hmat,
    const float* __restrict__ asrc, const float* __restrict__ adst,
    const int* __restrict__ offsets, const int* __restrict__ esrc,
    const float* __restrict__ bias, float* __restrict__ outv) {
  const int lane = threadIdx.x & 63, wid = threadIdx.x >> 6;
  const int g = lane >> 4, q = lane & 15;
  const int node = blockIdx.x * 16 + wid * 4 + g;
  if (node >= NNODES) return;
  const int start = offsets[node];
  const int end = offsets[node + 1];
  const float adn = adst[node];
  const _Float16* hbase = hmat + q * 4;
  float acc[4] = {0.f, 0.f, 0.f, 0.f};
  float s = 0.f;
  int j = start;
  for (; j + 4 <= end; j += 4) {
    int sv[4];
#pragma unroll
    for (int t = 0; t < 4; ++t) sv[t] = esrc[j + t];
    f16x4 v[4];
#pragma unroll
    for (int t = 0; t < 4; ++t) v[t] = *(const f16x4*)&hbase[(size_t)sv[t] * 64];
#pragma unroll
    for (int t = 0; t < 4; ++t) {
      float x = asrc[sv[t]] + adn;
      x = (x > 0.f) ? x : 0.2f * x;
      float p = __expf(x);
      s += p;
      _Float16 phs = (_Float16)p;
#pragma unroll
      for (int k = 0; k < 4; ++k) acc[k] = fmaf((float)v[t][k], (float)phs, acc[k]);
    }
  }
  for (; j < end; ++j) {
    int sv = esrc[j];
    f16x4 v = *(const f16x4*)&hbase[(size_t)sv * 64];
    float x = asrc[sv] + adn;
    x = (x > 0.f) ? x : 0.2f * x;
    float p = __expf(x);
    s += p;
    _Float16 phs = (_Float16)p;
#pragma unroll
    for (int k = 0; k < 4; ++k) acc[k] = fmaf((float)v[k], (float)phs, acc[k]);
  }
  float inv = 1.f / (s + 1e-16f);
  float4 o;
  o.x = fmaxf(fmaf(acc[0], inv, bias[q * 4 + 0]), 0.f);
  o.y = fmaxf(fmaf(acc[1], inv, bias[q * 4 + 1]), 0.f);
  o.z = fmaxf(fmaf(acc[2], inv, bias[q * 4 + 2]), 0.f);
  o.w = fmaxf(fmaf(acc[3], inv, bias[q * 4 + 3]), 0.f);
  *(float4*)&outv[(size_t)node * 64 + q * 4] = o;
}

// ---------------- fused global mean pool: one block per graph ----------------
__global__ __launch_bounds__(256) void pool_kernel(const float* __restrict__ g2,
    const int* __restrict__ batch, float* __restrict__ out, int n) {
  const int gid = blockIdx.x;
  const int lane = threadIdx.x & 63, w = threadIdx.x >> 6;
  // bounds via binary search (batch sorted); all threads compute identically
  int lo = 0, hi = n;
  while (lo < hi) { int mid = (lo + hi) >> 1; if (batch[mid] < gid) lo = mid + 1; else hi = mid; }
  int lb = lo;
  hi = n;
  while (lo < hi) { int mid = (lo + hi) >> 1; if (batch[mid] < gid + 1) lo = mid + 1; else hi = mid; }
  int ub = lo;
  float acc = 0.f;
  for (int i = lb + w; i < ub; i += 4) acc += g2[(size_t)i * 64 + lane];
  __shared__ float red[4][64];
  red[w][lane] = acc;
  __syncthreads();
  if (threadIdx.x < 64) {
    float sum = (red[0][lane] + red[1][lane]) + (red[2][lane] + red[3][lane]);
    float cnt = fmaxf((float)(ub - lb), 1.f);
    out[gid * 64 + lane] = sum / cnt;
  }
}

// ---------------- launcher ----------------
extern "C" void kernel_launch(void* const* d_in, const int* in_sizes, int n_in,
                              void* d_out, int out_size, void* d_ws, size_t ws_size,
                              hipStream_t stream) {
  const float* x      = (const float*)d_in[0];
  const float* w1     = (const float*)d_in[1];
  const float* a_src1 = (const float*)d_in[2];
  const float* a_dst1 = (const float*)d_in[3];
  const float* b1     = (const float*)d_in[4];
  const float* w2     = (const float*)d_in[5];
  const float* a_src2 = (const float*)d_in[6];
  const float* a_dst2 = (const float*)d_in[7];
  const float* b2     = (const float*)d_in[8];
  const int*   src    = (const int*)d_in[9];
  const int*   dst    = src + NEDGES;
  const int*   batch  = (const int*)d_in[10];
  float* out = (float*)d_out;

  const int N = NNODES, E = NEDGES;
  const int NB = (N + 1023) / 1024;

  char* wsb = (char*)d_ws;
  size_t off = 0;
  auto alloc = [&](size_t bytes) {
    void* p = wsb + off;
    off = (off + bytes + 255) & ~(size_t)255;
    return p;
  };
  _Float16* h1h = (_Float16*)alloc((size_t)N * 256 * 2);
  _Float16* g1h = (_Float16*)alloc((size_t)N * 256 * 2);
  _Float16* h2h = (_Float16*)alloc((size_t)N * 64 * 2);
  float* g2     = (float*)alloc((size_t)N * 64 * 4);
  float* as1    = (float*)alloc((size_t)N * 4 * 4);
  float* ad1    = (float*)alloc((size_t)N * 4 * 4);
  float* as2    = (float*)alloc((size_t)N * 4);
  float* ad2    = (float*)alloc((size_t)N * 4);
  int* deg      = (int*)alloc((size_t)N * 4);
  int* inc      = (int*)alloc((size_t)N * 4);
  int* bsum     = (int*)alloc((size_t)NB * 4);
  int* boff     = (int*)alloc((size_t)NB * 4);
  int* offsets  = (int*)alloc((size_t)(N + 1) * 4);
  int* cursor   = (int*)alloc((size_t)N * 4);
  int* esrc     = (int*)alloc((size_t)E * 4);

  // ---- CSR build ----
  hipMemsetAsync(deg, 0, (size_t)N * 4, stream);
  hist_kernel<<<(E + 255) / 256, 256, 0, stream>>>(dst, deg, E);
  scan1<<<NB, 1024, 0, stream>>>(deg, inc, bsum, N);
  scan2<<<1, 128, 0, stream>>>(bsum, boff, NB);
  scan3<<<(N + 255) / 256, 256, 0, stream>>>(inc, deg, boff, offsets, cursor, N, E);
  scatter_kernel<<<(E + 255) / 256, 256, 0, stream>>>(src, dst, cursor, esrc, E);

  // ---- layer 1 ----
  gemm_mfma<128, 256, float><<<(N + 63) / 64, 256, 0, stream>>>(
      x, w1, h1h, N, a_src1, a_dst1, as1, ad1);
  const int NH = 50000;  // split agg1 so the profiler surfaces the #2 kernel
  agg1_kernel<<<NH / 4, 256, 0, stream>>>(h1h, as1, ad1, offsets, esrc, b1, g1h, 0);
  agg1_kernel<<<(N - NH + 3) / 4, 256, 0, stream>>>(h1h, as1, ad1, offsets, esrc, b1, g1h, NH);

  // ---- layer 2 ----
  gemm_mfma<256, 64, _Float16><<<(N + 63) / 64, 256, 0, stream>>>(
      g1h, w2, h2h, N, a_src2, a_dst2, as2, ad2);
  agg2_kernel<<<(N + 15) / 16, 256, 0, stream>>>(h2h, as2, ad2, offsets, esrc, b2, g2);

  // ---- pool ----
  pool_kernel<<<NGRAPH, 256, 0, stream>>>(g2, batch, out, N);
}

// Round 10
// 410.386 us; speedup vs baseline: 1.3040x; 1.3040x over previous
//
#include <hip/hip_runtime.h>
#include <math.h>
#include <type_traits>

#define NNODES 100000
#define NEDGES 1600000
#define NGRAPH 128
#define NBKT 391          // dst buckets of 256 nodes
#define CAP 1536          // per (partition,bucket) capacity (mean 512 + 45 sigma)
#define EPB 2048          // edges per bucketA block

typedef _Float16 f16x4 __attribute__((ext_vector_type(4)));
typedef _Float16 f16x8 __attribute__((ext_vector_type(8)));
typedef float f32x4 __attribute__((ext_vector_type(4)));

// ------- MFMA GEMM + fused attention-logit epilogue -------
template <int K, int N, typename AT>
__global__ __launch_bounds__(256, 2) void gemm_mfma(const AT* __restrict__ A,
    const float* __restrict__ B, _Float16* __restrict__ C, int M,
    const float* __restrict__ a_src, const float* __restrict__ a_dst,
    float* __restrict__ asrc, float* __restrict__ adst) {
  constexpr int BM = 64;
  constexpr int H = N / 64;
  __shared__ _Float16 As[BM * K];
  __shared__ _Float16 Bs[N * K];
  const int tid = threadIdx.x;
  const int bm = blockIdx.x * BM;

  for (int i = tid * 4; i < BM * K; i += 1024) {
    int row = i / K;
    int k = i & (K - 1);
    int gr = bm + row;
    f16x4 h;
    if constexpr (std::is_same<AT, float>::value) {
      float4 v = {0.f, 0.f, 0.f, 0.f};
      if (gr < M) v = *(const float4*)&A[(size_t)gr * K + k];
      h[0] = (_Float16)v.x; h[1] = (_Float16)v.y; h[2] = (_Float16)v.z; h[3] = (_Float16)v.w;
    } else {
      f16x4 v = {};
      if (gr < M) v = *(const f16x4*)&A[(size_t)gr * K + k];
      h = v;
    }
    int idx = (row * K + k) ^ ((row & 7) << 3);
    *(f16x4*)&As[idx] = h;
  }
  for (int i = tid * 4; i < N * K; i += 1024) {
    int row = i / K;
    int k = i & (K - 1);
    float4 v = *(const float4*)&B[(size_t)row * K + k];
    f16x4 h;
    h[0] = (_Float16)v.x; h[1] = (_Float16)v.y; h[2] = (_Float16)v.z; h[3] = (_Float16)v.w;
    int idx = (row * K + k) ^ ((row & 7) << 3);
    *(f16x4*)&Bs[idx] = h;
  }
  __syncthreads();

  const int lane = tid & 63, wid = tid >> 6;
  const int lr = lane & 15;
  const int lk = (lane >> 4) * 8;
  constexpr int KS = K / 32, NT = N / 16;

  f16x8 a[KS];
#pragma unroll
  for (int ks = 0; ks < KS; ++ks) {
    int row = wid * 16 + lr;
    int idx = (row * K + ks * 32 + lk) ^ ((row & 7) << 3);
    a[ks] = *(const f16x8*)&As[idx];
  }

  f32x4 acc[NT];
#pragma unroll
  for (int nt = 0; nt < NT; ++nt) acc[nt] = (f32x4){0.f, 0.f, 0.f, 0.f};

#pragma unroll
  for (int nt = 0; nt < NT; ++nt)
#pragma unroll
    for (int ks = 0; ks < KS; ++ks) {
      int row = nt * 16 + lr;
      int idx = (row * K + ks * 32 + lk) ^ ((row & 7) << 3);
      f16x8 b = *(const f16x8*)&Bs[idx];
      acc[nt] = __builtin_amdgcn_mfma_f32_16x16x32_f16(a[ks], b, acc[nt], 0, 0, 0);
    }

  float cs[NT], cd[NT];
#pragma unroll
  for (int nt = 0; nt < NT; ++nt) {
    cs[nt] = a_src[nt * 16 + lr];
    cd[nt] = a_dst[nt * 16 + lr];
  }

  int row0 = bm + wid * 16 + (lane >> 4) * 4;
#pragma unroll
  for (int r = 0; r < 4; ++r) {
    int row = row0 + r;
    float ps[H], pd[H];
#pragma unroll
    for (int h = 0; h < H; ++h) { ps[h] = 0.f; pd[h] = 0.f; }
#pragma unroll
    for (int nt = 0; nt < NT; ++nt) {
      int h = nt >> 2;
      if (H == 1) h = 0;
      ps[h] = fmaf(acc[nt][r], cs[nt], ps[h]);
      pd[h] = fmaf(acc[nt][r], cd[nt], pd[h]);
    }
#pragma unroll
    for (int o = 1; o < 16; o <<= 1) {
#pragma unroll
      for (int h = 0; h < H; ++h) {
        ps[h] += __shfl_xor(ps[h], o);
        pd[h] += __shfl_xor(pd[h], o);
      }
    }
    if (row < M) {
#pragma unroll
      for (int nt = 0; nt < NT; ++nt) C[(size_t)row * N + nt * 16 + lr] = (_Float16)acc[nt][r];
      if (lr == 0) {
        if (H == 4) {
          *(float4*)&asrc[row * 4] = make_float4(ps[0], ps[1], ps[2], ps[3 % H]);
          *(float4*)&adst[row * 4] = make_float4(pd[0], pd[1], pd[2], pd[3 % H]);
        } else {
          asrc[row] = ps[0];
          adst[row] = pd[0];
        }
      }
    }
  }
}

// ---------------- CSR build: XCD-partitioned bucket sort ----------------
// Phase A: partition edges into (P=blockIdx&7, bucket=dst>>8) segments.
// Same-P blocks map (heuristically) to the same XCD -> segment lines stay in
// one L2, no cross-XCD line bouncing (the round-9 scatter cost).
__global__ __launch_bounds__(256) void bucketA(const int* __restrict__ srcv,
    const int* __restrict__ dstv, int2* __restrict__ part, int* __restrict__ gcur,
    int e_count) {
  __shared__ int hist[NBKT];
  __shared__ int base_[NBKT];
  __shared__ int lofs[NBKT];
  const int tid = threadIdx.x;
  const int P = blockIdx.x & 7;
  for (int i = tid; i < NBKT; i += 256) { hist[i] = 0; lofs[i] = 0; }
  __syncthreads();
  const int e0 = blockIdx.x * EPB;
  const int e1 = min(e0 + EPB, e_count);
  for (int e = e0 + tid; e < e1; e += 256) atomicAdd(&hist[dstv[e] >> 8], 1);
  __syncthreads();
  for (int i = tid; i < NBKT; i += 256) {
    int c = hist[i];
    base_[i] = c ? atomicAdd(&gcur[(P * NBKT + i) * 16], c) : 0;  // 64B-padded counter
  }
  __syncthreads();
  for (int e = e0 + tid; e < e1; e += 256) {
    int d = dstv[e];
    int b = d >> 8;
    int l = atomicAdd(&lofs[b], 1);
    part[(size_t)(P * NBKT + b) * CAP + base_[b] + l] = make_int2(srcv[e], d);
  }
}

// Phase B1: per-bucket degree count (LDS atomics only).
__global__ __launch_bounds__(256) void bucketB1(const int2* __restrict__ part,
    const int* __restrict__ gcur, int* __restrict__ deg, int n) {
  __shared__ int cnt[256];
  const int b = blockIdx.x;
  const int tid = threadIdx.x;
  cnt[tid] = 0;
  __syncthreads();
  for (int P = 0; P < 8; ++P) {
    int cn = gcur[(P * NBKT + b) * 16];
    const int2* seg = part + (size_t)(P * NBKT + b) * CAP;
    for (int i = tid; i < cn; i += 256) atomicAdd(&cnt[seg[i].y & 255], 1);
  }
  __syncthreads();
  int node = (b << 8) + tid;
  if (node < n) deg[node] = cnt[tid];
}

// Phase B2: place esrc; all writes land in this bucket's contiguous CSR region.
__global__ __launch_bounds__(256) void bucketB2(const int2* __restrict__ part,
    const int* __restrict__ gcur, const int* __restrict__ offsets,
    int* __restrict__ esrc, int n) {
  __shared__ int lcur[256];
  const int b = blockIdx.x;
  const int tid = threadIdx.x;
  int node = (b << 8) + tid;
  lcur[tid] = (node < n) ? offsets[node] : 0;
  __syncthreads();
  for (int P = 0; P < 8; ++P) {
    int cn = gcur[(P * NBKT + b) * 16];
    const int2* seg = part + (size_t)(P * NBKT + b) * CAP;
    for (int i = tid; i < cn; i += 256) {
      int2 e = seg[i];
      int slot = atomicAdd(&lcur[e.y & 255], 1);
      esrc[slot] = e.x;
    }
  }
}

__global__ __launch_bounds__(1024) void scan1(const int* __restrict__ deg, int* __restrict__ inc,
                                              int* __restrict__ bsum, int n) {
  __shared__ int sm[1024];
  int i = blockIdx.x * 1024 + threadIdx.x;
  sm[threadIdx.x] = (i < n) ? deg[i] : 0;
  __syncthreads();
  for (int o = 1; o < 1024; o <<= 1) {
    int t = (threadIdx.x >= o) ? sm[threadIdx.x - o] : 0;
    __syncthreads();
    sm[threadIdx.x] += t;
    __syncthreads();
  }
  if (i < n) inc[i] = sm[threadIdx.x];
  if (threadIdx.x == 1023) bsum[blockIdx.x] = sm[1023];
}

__global__ void scan2(const int* __restrict__ bsum, int* __restrict__ boff, int nb) {
  __shared__ int sm[128];
  int t = threadIdx.x;
  int own = (t < nb) ? bsum[t] : 0;
  sm[t] = own;
  __syncthreads();
  for (int o = 1; o < 128; o <<= 1) {
    int u = (t >= o) ? sm[t - o] : 0;
    __syncthreads();
    sm[t] += u;
    __syncthreads();
  }
  if (t < nb) boff[t] = sm[t] - own;
}

__global__ void scan3(const int* __restrict__ inc, const int* __restrict__ deg,
                      const int* __restrict__ boff, int* __restrict__ offsets,
                      int n, int e_count) {
  int i = blockIdx.x * blockDim.x + threadIdx.x;
  if (i < n) offsets[i] = inc[i] - deg[i] + boff[i >> 10];
  if (i == 0) offsets[n] = e_count;
}

// ------------- layer-1 aggregation: one WAVE per node, 8-deep gather pipeline ---
__global__ __launch_bounds__(256) void agg1_kernel(const _Float16* __restrict__ hmat,
    const float* __restrict__ asrc, const float* __restrict__ adst,
    const int* __restrict__ offsets, const int* __restrict__ esrc,
    const float* __restrict__ bias, _Float16* __restrict__ outv, int node0, int node_end) {
  const int lane = threadIdx.x & 63, wid = threadIdx.x >> 6;
  const int node = node0 + blockIdx.x * 4 + wid;
  if (node >= node_end) return;
  const int h = lane >> 4;
  const int start = offsets[node];
  const int end = offsets[node + 1];
  const float adn = adst[node * 4 + h];
  const _Float16* hbase = hmat + lane * 4;
  float acc[4] = {0.f, 0.f, 0.f, 0.f};
  float s = 0.f;
  int j = start;
  for (; j + 8 <= end; j += 8) {
    int sv[8];
#pragma unroll
    for (int t = 0; t < 8; ++t) sv[t] = esrc[j + t];
    f16x4 vv[8];
#pragma unroll
    for (int t = 0; t < 8; ++t) vv[t] = *(const f16x4*)&hbase[(size_t)sv[t] * 256];
    _Float16 ph[8];
#pragma unroll
    for (int t = 0; t < 8; ++t) {
      float v = asrc[sv[t] * 4 + h] + adn;
      v = (v > 0.f) ? v : 0.2f * v;
      float p = __expf(v);
      s += p;
      ph[t] = (_Float16)p;
    }
#pragma unroll
    for (int t = 0; t < 8; ++t)
#pragma unroll
      for (int k = 0; k < 4; ++k)
        acc[k] = fmaf((float)vv[t][k], (float)ph[t], acc[k]);  // v_fma_mix_f32
  }
  for (; j < end; ++j) {
    int sv = esrc[j];
    f16x4 vv = *(const f16x4*)&hbase[(size_t)sv * 256];
    float v = asrc[sv * 4 + h] + adn;
    v = (v > 0.f) ? v : 0.2f * v;
    float p = __expf(v);
    s += p;
    _Float16 phs = (_Float16)p;
#pragma unroll
    for (int k = 0; k < 4; ++k) acc[k] = fmaf((float)vv[k], (float)phs, acc[k]);
  }
  float inv = 1.f / (s + 1e-16f);
  f16x4 ho;
#pragma unroll
  for (int k = 0; k < 4; ++k)
    ho[k] = (_Float16)fmaxf(fmaf(acc[k], inv, bias[lane * 4 + k]), 0.f);
  *(f16x4*)&outv[(size_t)node * 256 + lane * 4] = ho;
}

// ------------- layer-2 aggregation: one NODE per 16-lane group ------------------
__global__ __launch_bounds__(256) void agg2_kernel(const _Float16* __restrict__ hmat,
    const float* __restrict__ asrc, const float* __restrict__ adst,
    const int* __restrict__ offsets, const int* __restrict__ esrc,
    const float* __restrict__ bias, float* __restrict__ outv) {
  const int lane = threadIdx.x & 63, wid = threadIdx.x >> 6;
  const int g = lane >> 4, q = lane & 15;
  const int node = blockIdx.x * 16 + wid * 4 + g;
  if (node >= NNODES) return;
  const int start = offsets[node];
  const int end = offsets[node + 1];
  const float adn = adst[node];
  const _Float16* hbase = hmat + q * 4;
  float acc[4] = {0.f, 0.f, 0.f, 0.f};
  float s = 0.f;
  int j = start;
  for (; j + 4 <= end; j += 4) {
    int sv[4];
#pragma unroll
    for (int t = 0; t < 4; ++t) sv[t] = esrc[j + t];
    f16x4 v[4];
#pragma unroll
    for (int t = 0; t < 4; ++t) v[t] = *(const f16x4*)&hbase[(size_t)sv[t] * 64];
#pragma unroll
    for (int t = 0; t < 4; ++t) {
      float x = asrc[sv[t]] + adn;
      x = (x > 0.f) ? x : 0.2f * x;
      float p = __expf(x);
      s += p;
      _Float16 phs = (_Float16)p;
#pragma unroll
      for (int k = 0; k < 4; ++k) acc[k] = fmaf((float)v[t][k], (float)phs, acc[k]);
    }
  }
  for (; j < end; ++j) {
    int sv = esrc[j];
    f16x4 v = *(const f16x4*)&hbase[(size_t)sv * 64];
    float x = asrc[sv] + adn;
    x = (x > 0.f) ? x : 0.2f * x;
    float p = __expf(x);
    s += p;
    _Float16 phs = (_Float16)p;
#pragma unroll
    for (int k = 0; k < 4; ++k) acc[k] = fmaf((float)v[k], (float)phs, acc[k]);
  }
  float inv = 1.f / (s + 1e-16f);
  float4 o;
  o.x = fmaxf(fmaf(acc[0], inv, bias[q * 4 + 0]), 0.f);
  o.y = fmaxf(fmaf(acc[1], inv, bias[q * 4 + 1]), 0.f);
  o.z = fmaxf(fmaf(acc[2], inv, bias[q * 4 + 2]), 0.f);
  o.w = fmaxf(fmaf(acc[3], inv, bias[q * 4 + 3]), 0.f);
  *(float4*)&outv[(size_t)node * 64 + q * 4] = o;
}

// ---------------- fused global mean pool ----------------
__global__ __launch_bounds__(256) void pool_kernel(const float* __restrict__ g2,
    const int* __restrict__ batch, float* __restrict__ out, int n) {
  const int gid = blockIdx.x;
  const int lane = threadIdx.x & 63, w = threadIdx.x >> 6;
  int lo = 0, hi = n;
  while (lo < hi) { int mid = (lo + hi) >> 1; if (batch[mid] < gid) lo = mid + 1; else hi = mid; }
  int lb = lo;
  hi = n;
  while (lo < hi) { int mid = (lo + hi) >> 1; if (batch[mid] < gid + 1) lo = mid + 1; else hi = mid; }
  int ub = lo;
  float acc = 0.f;
  for (int i = lb + w; i < ub; i += 4) acc += g2[(size_t)i * 64 + lane];
  __shared__ float red[4][64];
  red[w][lane] = acc;
  __syncthreads();
  if (threadIdx.x < 64) {
    float sum = (red[0][lane] + red[1][lane]) + (red[2][lane] + red[3][lane]);
    float cnt = fmaxf((float)(ub - lb), 1.f);
    out[gid * 64 + lane] = sum / cnt;
  }
}

// ---------------- launcher ----------------
extern "C" void kernel_launch(void* const* d_in, const int* in_sizes, int n_in,
                              void* d_out, int out_size, void* d_ws, size_t ws_size,
                              hipStream_t stream) {
  const float* x      = (const float*)d_in[0];
  const float* w1     = (const float*)d_in[1];
  const float* a_src1 = (const float*)d_in[2];
  const float* a_dst1 = (const float*)d_in[3];
  const float* b1     = (const float*)d_in[4];
  const float* w2     = (const float*)d_in[5];
  const float* a_src2 = (const float*)d_in[6];
  const float* a_dst2 = (const float*)d_in[7];
  const float* b2     = (const float*)d_in[8];
  const int*   src    = (const int*)d_in[9];
  const int*   dst    = src + NEDGES;
  const int*   batch  = (const int*)d_in[10];
  float* out = (float*)d_out;

  const int N = NNODES, E = NEDGES;
  const int NB = (N + 1023) / 1024;

  char* wsb = (char*)d_ws;
  size_t off = 0;
  auto alloc = [&](size_t bytes) {
    void* p = wsb + off;
    off = (off + bytes + 255) & ~(size_t)255;
    return p;
  };
  _Float16* h1h = (_Float16*)alloc((size_t)N * 256 * 2);
  _Float16* g1h = (_Float16*)alloc((size_t)N * 256 * 2);
  _Float16* h2h = (_Float16*)alloc((size_t)N * 64 * 2);
  float* g2     = (float*)alloc((size_t)N * 64 * 4);
  float* as1    = (float*)alloc((size_t)N * 4 * 4);
  float* ad1    = (float*)alloc((size_t)N * 4 * 4);
  float* as2    = (float*)alloc((size_t)N * 4);
  float* ad2    = (float*)alloc((size_t)N * 4);
  int* deg      = (int*)alloc((size_t)N * 4);
  int* inc      = (int*)alloc((size_t)N * 4);
  int* bsum     = (int*)alloc((size_t)NB * 4);
  int* boff     = (int*)alloc((size_t)NB * 4);
  int* offsets  = (int*)alloc((size_t)(N + 1) * 4);
  int* esrc     = (int*)alloc((size_t)E * 4);
  int2* part    = (int2*)alloc((size_t)8 * NBKT * CAP * 8);
  int* gcur     = (int*)alloc((size_t)8 * NBKT * 16 * 4);

  // ---- CSR build (bucket sort) ----
  hipMemsetAsync(gcur, 0, (size_t)8 * NBKT * 16 * 4, stream);
  bucketA<<<(E + EPB - 1) / EPB, 256, 0, stream>>>(src, dst, part, gcur, E);
  bucketB1<<<NBKT, 256, 0, stream>>>(part, gcur, deg, N);
  scan1<<<NB, 1024, 0, stream>>>(deg, inc, bsum, N);
  scan2<<<1, 128, 0, stream>>>(bsum, boff, NB);
  scan3<<<(N + 255) / 256, 256, 0, stream>>>(inc, deg, boff, offsets, N, E);
  bucketB2<<<NBKT, 256, 0, stream>>>(part, gcur, offsets, esrc, N);

  // ---- layer 1 ----
  gemm_mfma<128, 256, float><<<(N + 63) / 64, 256, 0, stream>>>(
      x, w1, h1h, N, a_src1, a_dst1, as1, ad1);
  // 3-way split: surfaces any kernel >~45us in next round's top-5
  agg1_kernel<<<8334, 256, 0, stream>>>(h1h, as1, ad1, offsets, esrc, b1, g1h, 0, 33336);
  agg1_kernel<<<8334, 256, 0, stream>>>(h1h, as1, ad1, offsets, esrc, b1, g1h, 33336, 66672);
  agg1_kernel<<<8332, 256, 0, stream>>>(h1h, as1, ad1, offsets, esrc, b1, g1h, 66672, 100000);

  // ---- layer 2 ----
  gemm_mfma<256, 64, _Float16><<<(N + 63) / 64, 256, 0, stream>>>(
      g1h, w2, h2h, N, a_src2, a_dst2, as2, ad2);
  agg2_kernel<<<(N + 15) / 16, 256, 0, stream>>>(h2h, as2, ad2, offsets, esrc, b2, g2);

  // ---- pool ----
  pool_kernel<<<NGRAPH, 256, 0, stream>>>(g2, batch, out, N);
}